// Round 1
// baseline (844.483 us; speedup 1.0000x reference)
//
#include <hip/hip_runtime.h>
#include <hip/hip_bf16.h>

#define T_SEQ 2048
#define NB 4
#define NE 2048
#define NH 16
#define NHKV 4
#define HD 128
#define KVD 512    // NHKV*HD
#define MTOT 8192  // NB*T_SEQ

typedef __attribute__((ext_vector_type(4))) float f32x4;
typedef __attribute__((ext_vector_type(8))) __bf16 bf16x8;

__device__ __forceinline__ unsigned short f2bf(float f) {
  union { float f; unsigned int u; } x; x.f = f;
  unsigned int u = x.u;
  unsigned int r = (u + 0x7fffu + ((u >> 16) & 1u)) >> 16;
  return (unsigned short)r;
}

typedef __attribute__((address_space(3))) unsigned int lds_uint;
typedef const __attribute__((address_space(1))) unsigned int glob_uint;

// async global->LDS, 16B per lane. lds base must be wave-uniform; HW writes
// lds_base + lane*16. Source address is per-lane.
__device__ __forceinline__ void gload_lds16(const void* g, void* l) {
  __builtin_amdgcn_global_load_lds((glob_uint*)g, (lds_uint*)l, 16, 0, 0);
}

// ---------------- cast f32 -> bf16, 8 elems/thread ----------------
__global__ __launch_bounds__(256) void k_cast(const float* __restrict__ in,
                                              unsigned short* __restrict__ out, int n) {
  int i = (blockIdx.x * blockDim.x + threadIdx.x) * 8;
  if (i >= n) return;
  float4 a = *(const float4*)(in + i);
  float4 b = *(const float4*)(in + i + 4);
  union { unsigned short us[8]; uint4 v; } o;
  o.us[0] = f2bf(a.x); o.us[1] = f2bf(a.y); o.us[2] = f2bf(a.z); o.us[3] = f2bf(a.w);
  o.us[4] = f2bf(b.x); o.us[5] = f2bf(b.y); o.us[6] = f2bf(b.z); o.us[7] = f2bf(b.w);
  *(uint4*)(out + i) = o.v;
}

// ---------------- transpose + cast: in[K][N] f32 -> out[N][K] bf16 ----------------
__global__ __launch_bounds__(256) void k_transpose_cast(const float* __restrict__ in,
                                                        unsigned short* __restrict__ out,
                                                        int K, int N) {
  __shared__ float tile[32][33];
  int n0 = blockIdx.x * 32, k0 = blockIdx.y * 32;
  int tx = threadIdx.x & 31, ty = threadIdx.x >> 5;  // ty 0..7
#pragma unroll
  for (int r = 0; r < 4; ++r)
    tile[ty + r * 8][tx] = in[(k0 + ty + r * 8) * N + n0 + tx];
  __syncthreads();
#pragma unroll
  for (int r = 0; r < 4; ++r)
    out[(n0 + ty + r * 8) * K + k0 + tx] = f2bf(tile[tx][ty + r * 8]);
}

// ---------------- GEMM: C[M,N] = A[M,K] @ Bt[N,K]^T (bf16 in, MFMA) ----------------
// STORE_MODE 0: bf16 row-major C. 1: bf16 transposed into Vt[b][n][t]. 2: f32 row-major.
// Tile 128x128, BK=32, 4 waves (each 64x64 = 4x4 frags of 16x16x32).
// LDS chunk swizzle: element (r,k): chunk c=k/8 stored at c ^ ((r>>1)&3).
template <int STORE_MODE>
__global__ __launch_bounds__(256) void k_gemm(const unsigned short* __restrict__ A,
                                              const unsigned short* __restrict__ Bt,
                                              void* __restrict__ C,
                                              int M, int N, int K) {
  __shared__ alignas(16) unsigned short lds[2][2][128 * 32];
  const int tid = threadIdx.x;
  const int w = tid >> 6, lane = tid & 63;
  const int lg = lane >> 4, ll = lane & 15;
  const int m0 = blockIdx.y * 128, n0 = blockIdx.x * 128;
  const int wr = (w >> 1) * 64, wc = (w & 1) * 64;

  f32x4 acc[4][4] = {};

  const int NT = K >> 5;
  int cur = 0;

  auto STAGE = [&](int buf, int t) {
    int k0 = t << 5;
#pragma unroll
    for (int is = 0; is < 2; ++is) {
      int chunk = is * 256 + tid;
      int r = chunk >> 2, c = chunk & 3;
      int sc = (c ^ ((r >> 1) & 3)) << 3;
      gload_lds16(A + (m0 + r) * K + k0 + sc, &lds[buf][0][(is * 256 + (w << 6)) * 8]);
      gload_lds16(Bt + (n0 + r) * K + k0 + sc, &lds[buf][1][(is * 256 + (w << 6)) * 8]);
    }
  };

  auto COMPUTE = [&](int buf) {
    const unsigned short* La = lds[buf][0];
    const unsigned short* Lb = lds[buf][1];
    bf16x8 af[4], bfr[4];
#pragma unroll
    for (int mf = 0; mf < 4; ++mf) {
      int r = wr + mf * 16 + ll;
      int c = lg ^ ((r >> 1) & 3);
      af[mf] = *(const bf16x8*)(La + r * 32 + c * 8);
    }
#pragma unroll
    for (int nf = 0; nf < 4; ++nf) {
      int r = wc + nf * 16 + ll;
      int c = lg ^ ((r >> 1) & 3);
      bfr[nf] = *(const bf16x8*)(Lb + r * 32 + c * 8);
    }
#pragma unroll
    for (int mf = 0; mf < 4; ++mf)
#pragma unroll
      for (int nf = 0; nf < 4; ++nf)
        acc[mf][nf] = __builtin_amdgcn_mfma_f32_16x16x32_bf16(af[mf], bfr[nf], acc[mf][nf], 0, 0, 0);
  };

  STAGE(0, 0);
  __syncthreads();
  for (int t = 0; t < NT - 1; ++t) {
    STAGE(cur ^ 1, t + 1);
    COMPUTE(cur);
    __syncthreads();
    cur ^= 1;
  }
  COMPUTE(cur);

  // epilogue: D layout row = 4*lg + i, col = ll (per 16x16 frag)
  if (STORE_MODE == 0) {
    unsigned short* Cp = (unsigned short*)C;
#pragma unroll
    for (int mf = 0; mf < 4; ++mf)
#pragma unroll
      for (int nf = 0; nf < 4; ++nf) {
        int row = m0 + wr + mf * 16 + (lg << 2);
        int col = n0 + wc + nf * 16 + ll;
#pragma unroll
        for (int i = 0; i < 4; ++i)
          Cp[(row + i) * N + col] = f2bf(acc[mf][nf][i]);
      }
  } else if (STORE_MODE == 2) {
    float* Cp = (float*)C;
#pragma unroll
    for (int mf = 0; mf < 4; ++mf)
#pragma unroll
      for (int nf = 0; nf < 4; ++nf) {
        int row = m0 + wr + mf * 16 + (lg << 2);
        int col = n0 + wc + nf * 16 + ll;
#pragma unroll
        for (int i = 0; i < 4; ++i)
          Cp[(row + i) * N + col] = acc[mf][nf][i];
      }
  } else {
    // Vt[b][n][t]: addr = (m>>11)*KVD*T + n*T + (m&2047); 4 consecutive m -> 8B store
    unsigned short* Cp = (unsigned short*)C;
#pragma unroll
    for (int mf = 0; mf < 4; ++mf)
#pragma unroll
      for (int nf = 0; nf < 4; ++nf) {
        int m = m0 + wr + mf * 16 + (lg << 2);
        int n = n0 + wc + nf * 16 + ll;
        int base = (m >> 11) * (KVD * T_SEQ) + n * T_SEQ + (m & 2047);
        union { unsigned short us[4]; uint2 v; } pk;
#pragma unroll
        for (int i = 0; i < 4; ++i) pk.us[i] = f2bf(acc[mf][nf][i]);
        *(uint2*)(Cp + base) = pk.v;
      }
  }
}

// ---------------- Flash attention with ALiBi + causal (GQA) ----------------
// Q:[MTOT][NE] bf16, Kp:[MTOT][KVD] bf16, Vt:[b][KVD][T] bf16, Y:[MTOT][NE] bf16
// Block: 128 q rows (4 waves x 32), KV tile = 64.
__global__ __launch_bounds__(256) void k_attn(const unsigned short* __restrict__ Q,
                                              const unsigned short* __restrict__ Kp,
                                              const unsigned short* __restrict__ Vt,
                                              unsigned short* __restrict__ Y) {
  __shared__ alignas(16) unsigned short Klds[64 * 128];   // [k][d], chunk c^= (r&7)
  __shared__ alignas(16) unsigned short Vlds[128 * 64];   // [d][k], chunk c^= (r&7)
  __shared__ alignas(16) unsigned short Plds[4][32 * 72]; // per-wave, pad stride 72

  const int tid = threadIdx.x, w = tid >> 6, lane = tid & 63;
  const int lg = lane >> 4, ll = lane & 15;
  const int qt = blockIdx.x, h = blockIdx.y, bb = blockIdx.z;
  const int q0 = qt * 128, hkv = h >> 2;
  const float slope = exp2f(-0.5f * (float)((h >> 2) + 1));
  const float scale = 0.08838834764831845f;  // 1/sqrt(128)
  const float L2E = 1.4426950408889634f;

  // Q fragments in registers: rows w*32 .. +31
  bf16x8 qf[2][4];
  {
    int qrow_base = bb * T_SEQ + q0 + w * 32;
#pragma unroll
    for (int qfi = 0; qfi < 2; ++qfi)
#pragma unroll
      for (int ds = 0; ds < 4; ++ds)
        qf[qfi][ds] = *(const bf16x8*)(Q + (qrow_base + qfi * 16 + ll) * NE + h * HD + ds * 32 + lg * 8);
  }

  f32x4 yacc[2][8] = {};
  float mrun[2][4], lrun[2][4];
#pragma unroll
  for (int a = 0; a < 2; ++a)
#pragma unroll
    for (int i = 0; i < 4; ++i) { mrun[a][i] = -1e30f; lrun[a][i] = 0.f; }

  const int nkt = (qt + 1) * 2;
  for (int kt = 0; kt < nkt; ++kt) {
    int kt0 = kt * 64;
    // stage K tile [64][128]: 16 chunks/row
#pragma unroll
    for (int is = 0; is < 4; ++is) {
      int chunk = is * 256 + tid;
      int r = chunk >> 4, c = chunk & 15;
      int sc = (c ^ (r & 7)) << 3;
      gload_lds16(Kp + (bb * T_SEQ + kt0 + r) * KVD + hkv * HD + sc,
                  &Klds[(is * 256 + w * 64) * 8]);
    }
    // stage Vt tile [128][64]: 8 chunks/row
#pragma unroll
    for (int is = 0; is < 4; ++is) {
      int chunk = is * 256 + tid;
      int r = chunk >> 3, c = chunk & 7;
      int sc = (c ^ (r & 7)) << 3;
      gload_lds16(Vt + (bb * KVD + hkv * HD + r) * T_SEQ + kt0 + sc,
                  &Vlds[(is * 256 + w * 64) * 8]);
    }
    __syncthreads();

    // S = Q @ K^T  (per wave: 32 q x 64 k)
    f32x4 sacc[2][4] = {};
#pragma unroll
    for (int ds = 0; ds < 4; ++ds) {
      bf16x8 kf[4];
#pragma unroll
      for (int kfi = 0; kfi < 4; ++kfi) {
        int r = kfi * 16 + ll;
        int c = (ds * 4 + lg) ^ (r & 7);
        kf[kfi] = *(const bf16x8*)(Klds + r * 128 + c * 8);
      }
#pragma unroll
      for (int qfi = 0; qfi < 2; ++qfi)
#pragma unroll
        for (int kfi = 0; kfi < 4; ++kfi)
          sacc[qfi][kfi] = __builtin_amdgcn_mfma_f32_16x16x32_bf16(qf[qfi][ds], kf[kfi], sacc[qfi][kfi], 0, 0, 0);
    }

    // scale + ALiBi + causal mask + online softmax
#pragma unroll
    for (int qfi = 0; qfi < 2; ++qfi) {
      float rmax[4];
#pragma unroll
      for (int i = 0; i < 4; ++i) {
        int q = q0 + w * 32 + qfi * 16 + lg * 4 + i;
        float mx = -1e30f;
#pragma unroll
        for (int kfi = 0; kfi < 4; ++kfi) {
          int k = kt0 + kfi * 16 + ll;
          float v = sacc[qfi][kfi][i] * scale + slope * (float)(k - q);
          v = (k <= q) ? v : -1e30f;
          sacc[qfi][kfi][i] = v;
          mx = fmaxf(mx, v);
        }
        rmax[i] = mx;
      }
#pragma unroll
      for (int j = 1; j < 16; j <<= 1)
#pragma unroll
        for (int i = 0; i < 4; ++i) rmax[i] = fmaxf(rmax[i], __shfl_xor(rmax[i], j, 64));
#pragma unroll
      for (int i = 0; i < 4; ++i) {
        float mnew = fmaxf(mrun[qfi][i], rmax[i]);
        float alpha = exp2f((mrun[qfi][i] - mnew) * L2E);
        mrun[qfi][i] = mnew;
        float rsum = 0.f;
#pragma unroll
        for (int kfi = 0; kfi < 4; ++kfi) {
          float p = exp2f((sacc[qfi][kfi][i] - mnew) * L2E);
          sacc[qfi][kfi][i] = p;
          rsum += p;
          Plds[w][(qfi * 16 + lg * 4 + i) * 72 + kfi * 16 + ll] = f2bf(p);
        }
#pragma unroll
        for (int j = 1; j < 16; j <<= 1) rsum += __shfl_xor(rsum, j, 64);
        lrun[qfi][i] = lrun[qfi][i] * alpha + rsum;
#pragma unroll
        for (int df = 0; df < 8; ++df) yacc[qfi][df][i] *= alpha;
      }
    }

    // PV: y += P @ V  (P from per-wave LDS, V from swizzled Vlds)
#pragma unroll
    for (int ks = 0; ks < 2; ++ks) {
      bf16x8 pf[2];
#pragma unroll
      for (int qfi = 0; qfi < 2; ++qfi)
        pf[qfi] = *(const bf16x8*)(&Plds[w][(qfi * 16 + ll) * 72 + ks * 32 + lg * 8]);
#pragma unroll
      for (int df = 0; df < 8; ++df) {
        int r = df * 16 + ll;
        int c = (ks * 4 + lg) ^ (r & 7);
        bf16x8 vf = *(const bf16x8*)(Vlds + r * 64 + c * 8);
#pragma unroll
        for (int qfi = 0; qfi < 2; ++qfi)
          yacc[qfi][df] = __builtin_amdgcn_mfma_f32_16x16x32_bf16(pf[qfi], vf, yacc[qfi][df], 0, 0, 0);
      }
    }
    __syncthreads();
  }

  // epilogue: normalize + store bf16
#pragma unroll
  for (int qfi = 0; qfi < 2; ++qfi)
#pragma unroll
    for (int i = 0; i < 4; ++i) {
      float inv = 1.f / lrun[qfi][i];
      int row = bb * T_SEQ + q0 + w * 32 + qfi * 16 + lg * 4 + i;
#pragma unroll
      for (int df = 0; df < 8; ++df)
        Y[row * NE + h * HD + df * 16 + ll] = f2bf(yacc[qfi][df][i] * inv);
    }
}

extern "C" void kernel_launch(void* const* d_in, const int* in_sizes, int n_in,
                              void* d_out, int out_size, void* d_ws, size_t ws_size,
                              hipStream_t stream) {
  const float* x = (const float*)d_in[0];
  const float* Wq = (const float*)d_in[1];
  const float* Wk = (const float*)d_in[2];
  const float* Wv = (const float*)d_in[3];
  const float* Wo = (const float*)d_in[4];

  unsigned short* ws = (unsigned short*)d_ws;
  unsigned short* xb  = ws;               // 16777216 (x bf16 [8192][2048]); reused as Y
  unsigned short* Wqt = ws + 16777216;    // 4194304  (Wq^T [2048][2048])
  unsigned short* Wkt = ws + 20971520;    // 1048576  (Wk^T [512][2048])
  unsigned short* Wvt = ws + 22020096;    // 1048576
  unsigned short* Wot = ws + 23068672;    // 4194304
  unsigned short* Qb  = ws + 27262976;    // 16777216 (Q [8192][2048])
  unsigned short* Kb  = ws + 44040192;    // 4194304  (K [8192][512])
  unsigned short* Vtb = ws + 48234496;    // 4194304  (V^T [4][512][2048])
  unsigned short* Yb  = xb;               // attn out reuses x region

  k_cast<<<8192, 256, 0, stream>>>(x, xb, 16777216);
  k_transpose_cast<<<dim3(64, 64), 256, 0, stream>>>(Wq, Wqt, 2048, 2048);
  k_transpose_cast<<<dim3(16, 64), 256, 0, stream>>>(Wk, Wkt, 2048, 512);
  k_transpose_cast<<<dim3(16, 64), 256, 0, stream>>>(Wv, Wvt, 2048, 512);
  k_transpose_cast<<<dim3(64, 64), 256, 0, stream>>>(Wo, Wot, 2048, 2048);

  k_gemm<0><<<dim3(16, 64), 256, 0, stream>>>(xb, Wqt, Qb, MTOT, 2048, 2048);
  k_gemm<0><<<dim3(4, 64), 256, 0, stream>>>(xb, Wkt, Kb, MTOT, 512, 2048);
  k_gemm<1><<<dim3(4, 64), 256, 0, stream>>>(xb, Wvt, Vtb, MTOT, 512, 2048);

  k_attn<<<dim3(16, 16, 4), 256, 0, stream>>>(Qb, Kb, Vtb, Yb);

  k_gemm<2><<<dim3(16, 64), 256, 0, stream>>>(Yb, Wot, d_out, MTOT, 2048, 2048);
}

// Round 2
// 782.402 us; speedup vs baseline: 1.0793x; 1.0793x over previous
//
#include <hip/hip_runtime.h>
#include <hip/hip_bf16.h>

#define T_SEQ 2048
#define NB 4
#define NE 2048
#define NH 16
#define NHKV 4
#define HD 128
#define KVD 512    // NHKV*HD
#define MTOT 8192  // NB*T_SEQ

typedef __attribute__((ext_vector_type(4))) float f32x4;
typedef __attribute__((ext_vector_type(8))) __bf16 bf16x8;

__device__ __forceinline__ unsigned short f2bf(float f) {
  union { float f; unsigned int u; } x; x.f = f;
  unsigned int u = x.u;
  unsigned int r = (u + 0x7fffu + ((u >> 16) & 1u)) >> 16;
  return (unsigned short)r;
}

typedef __attribute__((address_space(3))) unsigned int lds_uint;
typedef const __attribute__((address_space(1))) unsigned int glob_uint;

// async global->LDS, 16B per lane. lds base must be wave-uniform; HW writes
// lds_base + lane*16. Source address is per-lane.
__device__ __forceinline__ void gload_lds16(const void* g, void* l) {
  __builtin_amdgcn_global_load_lds((glob_uint*)g, (lds_uint*)l, 16, 0, 0);
}

// ---------------- cast f32 -> bf16, 8 elems/thread ----------------
__global__ __launch_bounds__(256) void k_cast(const float* __restrict__ in,
                                              unsigned short* __restrict__ out, int n) {
  int i = (blockIdx.x * blockDim.x + threadIdx.x) * 8;
  if (i >= n) return;
  float4 a = *(const float4*)(in + i);
  float4 b = *(const float4*)(in + i + 4);
  union { unsigned short us[8]; uint4 v; } o;
  o.us[0] = f2bf(a.x); o.us[1] = f2bf(a.y); o.us[2] = f2bf(a.z); o.us[3] = f2bf(a.w);
  o.us[4] = f2bf(b.x); o.us[5] = f2bf(b.y); o.us[6] = f2bf(b.z); o.us[7] = f2bf(b.w);
  *(uint4*)(out + i) = o.v;
}

// ---------------- transpose + cast: in[K][N] f32 -> out[N][K] bf16 ----------------
__global__ __launch_bounds__(256) void k_transpose_cast(const float* __restrict__ in,
                                                        unsigned short* __restrict__ out,
                                                        int K, int N) {
  __shared__ float tile[32][33];
  int n0 = blockIdx.x * 32, k0 = blockIdx.y * 32;
  int tx = threadIdx.x & 31, ty = threadIdx.x >> 5;  // ty 0..7
#pragma unroll
  for (int r = 0; r < 4; ++r)
    tile[ty + r * 8][tx] = in[(k0 + ty + r * 8) * N + n0 + tx];
  __syncthreads();
#pragma unroll
  for (int r = 0; r < 4; ++r)
    out[(n0 + ty + r * 8) * K + k0 + tx] = f2bf(tile[tx][ty + r * 8]);
}

// ---------------- GEMM: C[M,N] = A[M,K] @ Bt[N,K]^T (bf16 in, MFMA) ----------------
template <int STORE_MODE>
__global__ __launch_bounds__(256) void k_gemm(const unsigned short* __restrict__ A,
                                              const unsigned short* __restrict__ Bt,
                                              void* __restrict__ C,
                                              int M, int N, int K) {
  __shared__ alignas(16) unsigned short lds[2][2][128 * 32];
  const int tid = threadIdx.x;
  const int w = tid >> 6, lane = tid & 63;
  const int lg = lane >> 4, ll = lane & 15;
  const int m0 = blockIdx.y * 128, n0 = blockIdx.x * 128;
  const int wr = (w >> 1) * 64, wc = (w & 1) * 64;

  f32x4 acc[4][4] = {};

  const int NT = K >> 5;
  int cur = 0;

  auto STAGE = [&](int buf, int t) {
    int k0 = t << 5;
#pragma unroll
    for (int is = 0; is < 2; ++is) {
      int chunk = is * 256 + tid;
      int r = chunk >> 2, c = chunk & 3;
      int sc = (c ^ ((r >> 1) & 3)) << 3;
      gload_lds16(A + (m0 + r) * K + k0 + sc, &lds[buf][0][(is * 256 + (w << 6)) * 8]);
      gload_lds16(Bt + (n0 + r) * K + k0 + sc, &lds[buf][1][(is * 256 + (w << 6)) * 8]);
    }
  };

  auto COMPUTE = [&](int buf) {
    const unsigned short* La = lds[buf][0];
    const unsigned short* Lb = lds[buf][1];
    bf16x8 af[4], bfr[4];
#pragma unroll
    for (int mf = 0; mf < 4; ++mf) {
      int r = wr + mf * 16 + ll;
      int c = lg ^ ((r >> 1) & 3);
      af[mf] = *(const bf16x8*)(La + r * 32 + c * 8);
    }
#pragma unroll
    for (int nf = 0; nf < 4; ++nf) {
      int r = wc + nf * 16 + ll;
      int c = lg ^ ((r >> 1) & 3);
      bfr[nf] = *(const bf16x8*)(Lb + r * 32 + c * 8);
    }
#pragma unroll
    for (int mf = 0; mf < 4; ++mf)
#pragma unroll
      for (int nf = 0; nf < 4; ++nf)
        acc[mf][nf] = __builtin_amdgcn_mfma_f32_16x16x32_bf16(af[mf], bfr[nf], acc[mf][nf], 0, 0, 0);
  };

  STAGE(0, 0);
  __syncthreads();
  for (int t = 0; t < NT - 1; ++t) {
    STAGE(cur ^ 1, t + 1);
    COMPUTE(cur);
    __syncthreads();
    cur ^= 1;
  }
  COMPUTE(cur);

  if (STORE_MODE == 0) {
    unsigned short* Cp = (unsigned short*)C;
#pragma unroll
    for (int mf = 0; mf < 4; ++mf)
#pragma unroll
      for (int nf = 0; nf < 4; ++nf) {
        int row = m0 + wr + mf * 16 + (lg << 2);
        int col = n0 + wc + nf * 16 + ll;
#pragma unroll
        for (int i = 0; i < 4; ++i)
          Cp[(row + i) * N + col] = f2bf(acc[mf][nf][i]);
      }
  } else if (STORE_MODE == 2) {
    float* Cp = (float*)C;
#pragma unroll
    for (int mf = 0; mf < 4; ++mf)
#pragma unroll
      for (int nf = 0; nf < 4; ++nf) {
        int row = m0 + wr + mf * 16 + (lg << 2);
        int col = n0 + wc + nf * 16 + ll;
#pragma unroll
        for (int i = 0; i < 4; ++i)
          Cp[(row + i) * N + col] = acc[mf][nf][i];
      }
  } else {
    unsigned short* Cp = (unsigned short*)C;
#pragma unroll
    for (int mf = 0; mf < 4; ++mf)
#pragma unroll
      for (int nf = 0; nf < 4; ++nf) {
        int m = m0 + wr + mf * 16 + (lg << 2);
        int n = n0 + wc + nf * 16 + ll;
        int base = (m >> 11) * (KVD * T_SEQ) + n * T_SEQ + (m & 2047);
        union { unsigned short us[4]; uint2 v; } pk;
#pragma unroll
        for (int i = 0; i < 4; ++i) pk.us[i] = f2bf(acc[mf][nf][i]);
        *(uint2*)(Cp + base) = pk.v;
      }
  }
}

// ---------------- Flash attention, ALiBi + causal, GQA ----------------
// Paired Q-tiles (qt, 15-qt) per block: constant 68 KVBLK=32 iterations.
// Double-buffered K/V with counted vmcnt(4) (prefetch stays in flight).
__global__ __launch_bounds__(256) void k_attn(const unsigned short* __restrict__ Q,
                                              const unsigned short* __restrict__ Kp,
                                              const unsigned short* __restrict__ Vt,
                                              unsigned short* __restrict__ Y) {
  __shared__ alignas(16) unsigned short Klds[2][32 * 128];  // [k][d], chunk c ^= (r&7)
  __shared__ alignas(16) unsigned short Vlds[2][128 * 32];  // [d][k], chunk c ^= ((r>>1)&3)
  __shared__ alignas(16) unsigned short Plds[4][32 * 40];   // per-wave, stride 40

  const int tid = threadIdx.x, w = tid >> 6, lane = tid & 63;
  const int lg = lane >> 4, ll = lane & 15;
  const int h = blockIdx.y, bb = blockIdx.z;
  const int hkv = h >> 2;
  const float L2E = 1.4426950408889634f;
  const float slopeL2 = exp2f(-0.5f * (float)((h >> 2) + 1)) * L2E;
  const float c0 = 0.08838834764831845f * L2E;  // (1/sqrt(128))*log2e

  const unsigned short* Kbase = Kp + (size_t)bb * T_SEQ * KVD + hkv * HD;
  const unsigned short* Vbase = Vt + ((size_t)bb * KVD + hkv * HD) * T_SEQ;

  for (int pi = 0; pi < 2; ++pi) {
    const int qt = pi ? (15 - (int)blockIdx.x) : (int)blockIdx.x;
    const int q0 = qt * 128;

    bf16x8 qf[2][4];
    {
      int qrow_base = bb * T_SEQ + q0 + w * 32;
#pragma unroll
      for (int qfi = 0; qfi < 2; ++qfi)
#pragma unroll
        for (int ds = 0; ds < 4; ++ds)
          qf[qfi][ds] = *(const bf16x8*)(Q + (size_t)(qrow_base + qfi * 16 + ll) * NE + h * HD + ds * 32 + lg * 8);
    }

    f32x4 yacc[2][8] = {};
    float m2[2][4], lr[2][4], qb[2][4];
#pragma unroll
    for (int qfi = 0; qfi < 2; ++qfi)
#pragma unroll
      for (int i = 0; i < 4; ++i) {
        m2[qfi][i] = -1e30f; lr[qfi][i] = 0.f;
        qb[qfi][i] = slopeL2 * (float)(q0 + w * 32 + qfi * 16 + lg * 4 + i);
      }

    auto STAGE = [&](int buf, int kt) {
      int kt0 = kt * 32;
#pragma unroll
      for (int is = 0; is < 2; ++is) {  // K: 32 rows x 16 chunks
        int chunk = is * 256 + tid;
        int r = chunk >> 4, c = chunk & 15;
        int sc = (c ^ (r & 7)) << 3;
        gload_lds16(Kbase + (size_t)(kt0 + r) * KVD + sc, &Klds[buf][(is * 256 + w * 64) * 8]);
      }
#pragma unroll
      for (int is = 0; is < 2; ++is) {  // V: 128 rows x 4 chunks
        int chunk = is * 256 + tid;
        int r = chunk >> 2, c = chunk & 3;
        int sc = (c ^ ((r >> 1) & 3)) << 3;
        gload_lds16(Vbase + (size_t)r * T_SEQ + kt0 + sc, &Vlds[buf][(is * 256 + w * 64) * 8]);
      }
    };

    const int nkt = 4 * (qt + 1);
    int cur = 0;
    STAGE(0, 0);
    for (int kt = 0; kt < nkt; ++kt) {
      if (kt + 1 < nkt) {
        STAGE(cur ^ 1, kt + 1);
        asm volatile("s_waitcnt vmcnt(4)" ::: "memory");  // current tile landed; prefetch in flight
      } else {
        asm volatile("s_waitcnt vmcnt(0)" ::: "memory");
      }
      __builtin_amdgcn_s_barrier();
      __builtin_amdgcn_sched_barrier(0);

      const unsigned short* Kl = Klds[cur];
      const unsigned short* Vl = Vlds[cur];
      const int kt0 = kt * 32;
      const bool masked = kt >= nkt - 4;

      // S = Q @ K^T (per wave: 32 q x 32 k)
      f32x4 sacc[2][2] = {};
#pragma unroll
      for (int ds = 0; ds < 4; ++ds) {
        bf16x8 kf[2];
#pragma unroll
        for (int kfi = 0; kfi < 2; ++kfi) {
          int r = kfi * 16 + ll;
          int c = (ds * 4 + lg) ^ (r & 7);
          kf[kfi] = *(const bf16x8*)(Kl + r * 128 + c * 8);
        }
#pragma unroll
        for (int qfi = 0; qfi < 2; ++qfi)
#pragma unroll
          for (int kfi = 0; kfi < 2; ++kfi)
            sacc[qfi][kfi] = __builtin_amdgcn_mfma_f32_16x16x32_bf16(qf[qfi][ds], kf[kfi], sacc[qfi][kfi], 0, 0, 0);
      }

      // log2-domain online softmax: v2 = S*scale*log2e + slope*log2e*(k-q)
      float bk0 = slopeL2 * (float)(kt0 + ll);
      float bk1 = slopeL2 * (float)(kt0 + 16 + ll);
#pragma unroll
      for (int qfi = 0; qfi < 2; ++qfi) {
        float rmax[4], a0v[4], a1v[4];
#pragma unroll
        for (int i = 0; i < 4; ++i) {
          float a0 = fmaf(sacc[qfi][0][i], c0, bk0) - qb[qfi][i];
          float a1 = fmaf(sacc[qfi][1][i], c0, bk1) - qb[qfi][i];
          if (masked) {
            int q = q0 + w * 32 + qfi * 16 + lg * 4 + i;
            a0 = (kt0 + ll <= q) ? a0 : -1e30f;
            a1 = (kt0 + 16 + ll <= q) ? a1 : -1e30f;
          }
          a0v[i] = a0; a1v[i] = a1;
          rmax[i] = fmaxf(a0, a1);
        }
#pragma unroll
        for (int j = 1; j < 16; j <<= 1)
#pragma unroll
          for (int i = 0; i < 4; ++i) rmax[i] = fmaxf(rmax[i], __shfl_xor(rmax[i], j, 64));
#pragma unroll
        for (int i = 0; i < 4; ++i) {
          float mnew = fmaxf(m2[qfi][i], rmax[i]);
          float alpha = exp2f(m2[qfi][i] - mnew);
          m2[qfi][i] = mnew;
          float p0 = exp2f(a0v[i] - mnew);
          float p1 = exp2f(a1v[i] - mnew);
          int prow = qfi * 16 + lg * 4 + i;
          Plds[w][prow * 40 + ll] = f2bf(p0);
          Plds[w][prow * 40 + 16 + ll] = f2bf(p1);
          float rsum = p0 + p1;
#pragma unroll
          for (int j = 1; j < 16; j <<= 1) rsum += __shfl_xor(rsum, j, 64);
          lr[qfi][i] = lr[qfi][i] * alpha + rsum;
#pragma unroll
          for (int df = 0; df < 8; ++df) yacc[qfi][df][i] *= alpha;
        }
      }

      // PV: y += P @ V
      bf16x8 pf[2];
#pragma unroll
      for (int qfi = 0; qfi < 2; ++qfi)
        pf[qfi] = *(const bf16x8*)(&Plds[w][(qfi * 16 + ll) * 40 + lg * 8]);
#pragma unroll
      for (int df = 0; df < 8; ++df) {
        int r = df * 16 + ll;
        int c = lg ^ ((r >> 1) & 3);
        bf16x8 vf = *(const bf16x8*)(Vl + r * 32 + c * 8);
#pragma unroll
        for (int qfi = 0; qfi < 2; ++qfi)
          yacc[qfi][df] = __builtin_amdgcn_mfma_f32_16x16x32_bf16(pf[qfi], vf, yacc[qfi][df], 0, 0, 0);
      }
      __builtin_amdgcn_sched_barrier(0);
      __builtin_amdgcn_s_barrier();
      cur ^= 1;
    }

    // epilogue: normalize + store bf16
#pragma unroll
    for (int qfi = 0; qfi < 2; ++qfi)
#pragma unroll
      for (int i = 0; i < 4; ++i) {
        float inv = 1.f / lr[qfi][i];
        size_t row = (size_t)bb * T_SEQ + q0 + w * 32 + qfi * 16 + lg * 4 + i;
#pragma unroll
        for (int df = 0; df < 8; ++df)
          Y[row * NE + h * HD + df * 16 + ll] = f2bf(yacc[qfi][df][i] * inv);
      }
  }
}

extern "C" void kernel_launch(void* const* d_in, const int* in_sizes, int n_in,
                              void* d_out, int out_size, void* d_ws, size_t ws_size,
                              hipStream_t stream) {
  const float* x = (const float*)d_in[0];
  const float* Wq = (const float*)d_in[1];
  const float* Wk = (const float*)d_in[2];
  const float* Wv = (const float*)d_in[3];
  const float* Wo = (const float*)d_in[4];

  unsigned short* ws = (unsigned short*)d_ws;
  unsigned short* xb  = ws;               // x bf16 [8192][2048]; reused as Y
  unsigned short* Wqt = ws + 16777216;
  unsigned short* Wkt = ws + 20971520;
  unsigned short* Wvt = ws + 22020096;
  unsigned short* Wot = ws + 23068672;
  unsigned short* Qb  = ws + 27262976;
  unsigned short* Kb  = ws + 44040192;
  unsigned short* Vtb = ws + 48234496;
  unsigned short* Yb  = xb;

  k_cast<<<8192, 256, 0, stream>>>(x, xb, 16777216);
  k_transpose_cast<<<dim3(64, 64), 256, 0, stream>>>(Wq, Wqt, 2048, 2048);
  k_transpose_cast<<<dim3(16, 64), 256, 0, stream>>>(Wk, Wkt, 2048, 512);
  k_transpose_cast<<<dim3(16, 64), 256, 0, stream>>>(Wv, Wvt, 2048, 512);
  k_transpose_cast<<<dim3(64, 64), 256, 0, stream>>>(Wo, Wot, 2048, 2048);

  k_gemm<0><<<dim3(16, 64), 256, 0, stream>>>(xb, Wqt, Qb, MTOT, 2048, 2048);
  k_gemm<0><<<dim3(4, 64), 256, 0, stream>>>(xb, Wkt, Kb, MTOT, 512, 2048);
  k_gemm<1><<<dim3(4, 64), 256, 0, stream>>>(xb, Wvt, Vtb, MTOT, 512, 2048);

  k_attn<<<dim3(8, 16, 4), 256, 0, stream>>>(Qb, Kb, Vtb, Yb);

  k_gemm<2><<<dim3(16, 64), 256, 0, stream>>>(Yb, Wot, d_out, MTOT, 2048, 2048);
}

// Round 3
// 518.726 us; speedup vs baseline: 1.6280x; 1.5083x over previous
//
#include <hip/hip_runtime.h>
#include <hip/hip_bf16.h>

#define T_SEQ 2048
#define NB 4
#define NE 2048
#define NH 16
#define NHKV 4
#define HD 128
#define KVD 512    // NHKV*HD
#define MTOT 8192  // NB*T_SEQ

typedef __attribute__((ext_vector_type(4))) float f32x4;
typedef __attribute__((ext_vector_type(16))) float f32x16;
typedef __attribute__((ext_vector_type(8))) __bf16 bf16x8;

__device__ __forceinline__ unsigned short f2bf(float f) {
  union { float f; unsigned int u; } x; x.f = f;
  unsigned int u = x.u;
  unsigned int r = (u + 0x7fffu + ((u >> 16) & 1u)) >> 16;
  return (unsigned short)r;
}

// v_cvt_pk_bf16_f32: dst.lo16 = bf16(lo), dst.hi16 = bf16(hi)
__device__ __forceinline__ unsigned cvtpk(float lo, float hi) {
  unsigned r;
  asm("v_cvt_pk_bf16_f32 %0, %1, %2" : "=v"(r) : "v"(lo), "v"(hi));
  return r;
}

// v_permlane32_swap_b32 a, b: swaps a's upper-32-lane half with b's lower-32-lane half.
// after: a = {lanes<32: old a | lanes>=32: old b[l-32]}
//        b = {lanes<32: old a[l+32] | lanes>=32: old b}
__device__ __forceinline__ void plswap(unsigned &a, unsigned &b) {
  asm volatile("v_permlane32_swap_b32 %0, %1" : "+v"(a), "+v"(b));
}

typedef __attribute__((address_space(3))) unsigned int lds_uint;
typedef const __attribute__((address_space(1))) unsigned int glob_uint;

__device__ __forceinline__ void gload_lds16(const void* g, void* l) {
  __builtin_amdgcn_global_load_lds((glob_uint*)g, (lds_uint*)l, 16, 0, 0);
}

// ---------------- cast f32 -> bf16, 8 elems/thread ----------------
__global__ __launch_bounds__(256) void k_cast(const float* __restrict__ in,
                                              unsigned short* __restrict__ out, int n) {
  int i = (blockIdx.x * blockDim.x + threadIdx.x) * 8;
  if (i >= n) return;
  float4 a = *(const float4*)(in + i);
  float4 b = *(const float4*)(in + i + 4);
  union { unsigned short us[8]; uint4 v; } o;
  o.us[0] = f2bf(a.x); o.us[1] = f2bf(a.y); o.us[2] = f2bf(a.z); o.us[3] = f2bf(a.w);
  o.us[4] = f2bf(b.x); o.us[5] = f2bf(b.y); o.us[6] = f2bf(b.z); o.us[7] = f2bf(b.w);
  *(uint4*)(out + i) = o.v;
}

// ---------------- transpose + cast: in[K][N] f32 -> out[N][K] bf16 ----------------
__global__ __launch_bounds__(256) void k_transpose_cast(const float* __restrict__ in,
                                                        unsigned short* __restrict__ out,
                                                        int K, int N) {
  __shared__ float tile[32][33];
  int n0 = blockIdx.x * 32, k0 = blockIdx.y * 32;
  int tx = threadIdx.x & 31, ty = threadIdx.x >> 5;
#pragma unroll
  for (int r = 0; r < 4; ++r)
    tile[ty + r * 8][tx] = in[(k0 + ty + r * 8) * N + n0 + tx];
  __syncthreads();
#pragma unroll
  for (int r = 0; r < 4; ++r)
    out[(n0 + ty + r * 8) * K + k0 + tx] = f2bf(tile[tx][ty + r * 8]);
}

// ---------------- GEMM: C[M,N] = A[M,K] @ Bt[N,K]^T (bf16 in, MFMA) ----------------
template <int STORE_MODE>
__global__ __launch_bounds__(256) void k_gemm(const unsigned short* __restrict__ A,
                                              const unsigned short* __restrict__ Bt,
                                              void* __restrict__ C,
                                              int M, int N, int K) {
  __shared__ alignas(16) unsigned short lds[2][2][128 * 32];
  const int tid = threadIdx.x;
  const int w = tid >> 6, lane = tid & 63;
  const int lg = lane >> 4, ll = lane & 15;
  const int m0 = blockIdx.y * 128, n0 = blockIdx.x * 128;
  const int wr = (w >> 1) * 64, wc = (w & 1) * 64;

  f32x4 acc[4][4] = {};

  const int NT = K >> 5;
  int cur = 0;

  auto STAGE = [&](int buf, int t) {
    int k0 = t << 5;
#pragma unroll
    for (int is = 0; is < 2; ++is) {
      int chunk = is * 256 + tid;
      int r = chunk >> 2, c = chunk & 3;
      int sc = (c ^ ((r >> 1) & 3)) << 3;
      gload_lds16(A + (m0 + r) * K + k0 + sc, &lds[buf][0][(is * 256 + (w << 6)) * 8]);
      gload_lds16(Bt + (n0 + r) * K + k0 + sc, &lds[buf][1][(is * 256 + (w << 6)) * 8]);
    }
  };

  auto COMPUTE = [&](int buf) {
    const unsigned short* La = lds[buf][0];
    const unsigned short* Lb = lds[buf][1];
    bf16x8 af[4], bfr[4];
#pragma unroll
    for (int mf = 0; mf < 4; ++mf) {
      int r = wr + mf * 16 + ll;
      int c = lg ^ ((r >> 1) & 3);
      af[mf] = *(const bf16x8*)(La + r * 32 + c * 8);
    }
#pragma unroll
    for (int nf = 0; nf < 4; ++nf) {
      int r = wc + nf * 16 + ll;
      int c = lg ^ ((r >> 1) & 3);
      bfr[nf] = *(const bf16x8*)(Lb + r * 32 + c * 8);
    }
#pragma unroll
    for (int mf = 0; mf < 4; ++mf)
#pragma unroll
      for (int nf = 0; nf < 4; ++nf)
        acc[mf][nf] = __builtin_amdgcn_mfma_f32_16x16x32_bf16(af[mf], bfr[nf], acc[mf][nf], 0, 0, 0);
  };

  STAGE(0, 0);
  __syncthreads();
  for (int t = 0; t < NT - 1; ++t) {
    STAGE(cur ^ 1, t + 1);
    COMPUTE(cur);
    __syncthreads();
    cur ^= 1;
  }
  COMPUTE(cur);

  if (STORE_MODE == 0) {
    unsigned short* Cp = (unsigned short*)C;
#pragma unroll
    for (int mf = 0; mf < 4; ++mf)
#pragma unroll
      for (int nf = 0; nf < 4; ++nf) {
        int row = m0 + wr + mf * 16 + (lg << 2);
        int col = n0 + wc + nf * 16 + ll;
#pragma unroll
        for (int i = 0; i < 4; ++i)
          Cp[(row + i) * N + col] = f2bf(acc[mf][nf][i]);
      }
  } else if (STORE_MODE == 2) {
    float* Cp = (float*)C;
#pragma unroll
    for (int mf = 0; mf < 4; ++mf)
#pragma unroll
      for (int nf = 0; nf < 4; ++nf) {
        int row = m0 + wr + mf * 16 + (lg << 2);
        int col = n0 + wc + nf * 16 + ll;
#pragma unroll
        for (int i = 0; i < 4; ++i)
          Cp[(row + i) * N + col] = acc[mf][nf][i];
      }
  } else {
    unsigned short* Cp = (unsigned short*)C;
#pragma unroll
    for (int mf = 0; mf < 4; ++mf)
#pragma unroll
      for (int nf = 0; nf < 4; ++nf) {
        int m = m0 + wr + mf * 16 + (lg << 2);
        int n = n0 + wc + nf * 16 + ll;
        int base = (m >> 11) * (KVD * T_SEQ) + n * T_SEQ + (m & 2047);
        union { unsigned short us[4]; uint2 v; } pk;
#pragma unroll
        for (int i = 0; i < 4; ++i) pk.us[i] = f2bf(acc[mf][nf][i]);
        *(uint2*)(Cp + base) = pk.v;
      }
  }
}

// ---------------- Flash attention, ALiBi + causal, GQA — swapped-operand 32x32 ----------------
// S^T = mfma32(K, Q^T): lane owns q = lane&31; k lane-local -> in-register softmax.
// PV swapped: y^T = mfma32(V^T, P^T). P redistributed via cvt_pk + permlane32_swap.
// Paired Q-tiles (qt, 15-qt): constant 34 KVBLK=64 tiles per block.
__global__ __launch_bounds__(256, 2) void k_attn(const unsigned short* __restrict__ Q,
                                                 const unsigned short* __restrict__ Kp,
                                                 const unsigned short* __restrict__ Vt,
                                                 unsigned short* __restrict__ Y) {
  __shared__ alignas(16) unsigned short Klds[2][64 * 128];  // [k][d], 16B chunk c ^= (k&15)
  __shared__ alignas(16) unsigned short Vlds[2][128 * 64];  // [d][k], 16B chunk c ^= (d&7)

  const int tid = threadIdx.x, w = tid >> 6, lane = tid & 63;
  const int l31 = lane & 31, hi = lane >> 5;
  const int h = blockIdx.y, bb = blockIdx.z;
  const int hkv = h >> 2;
  const float L2E = 1.4426950408889634f;
  const float slopeL2 = exp2f(-0.5f * (float)(hkv + 1)) * L2E;
  const float c0 = 0.08838834764831845f * L2E;  // (1/sqrt(128))*log2e

  const unsigned short* Kbase = Kp + (size_t)bb * T_SEQ * KVD + hkv * HD;
  const unsigned short* Vbase = Vt + ((size_t)bb * KVD + hkv * HD) * T_SEQ;

  for (int pi = 0; pi < 2; ++pi) {
    const int qt = pi ? (15 - (int)blockIdx.x) : (int)blockIdx.x;
    const int q0 = qt * 128;
    const int qbase = q0 + w * 32;
    const int qrow = bb * T_SEQ + qbase + l31;

    // Q^T B-fragments: lane needs Q[q][ds*16 + hi*8 .. +8] — contiguous 16B per slice
    bf16x8 qf[8];
#pragma unroll
    for (int ds = 0; ds < 8; ++ds)
      qf[ds] = *(const bf16x8*)(Q + (size_t)qrow * NE + h * HD + ds * 16 + hi * 8);

    f32x16 yacc[4] = {};
    float mrun = -1e30f, lrun = 0.f;
    const float qbias = slopeL2 * (float)(qbase + l31);

    auto STAGE = [&](int buf, int kt) {
      int kt0 = kt * 64;
#pragma unroll
      for (int is = 0; is < 4; ++is) {  // K: 64 rows x 16 chunks
        int chunk = is * 256 + tid;
        int r = chunk >> 4, c = chunk & 15;
        gload_lds16(Kbase + (size_t)(kt0 + r) * KVD + ((c ^ (r & 15)) << 3),
                    &Klds[buf][(is * 256 + w * 64) * 8]);
      }
#pragma unroll
      for (int is = 0; is < 4; ++is) {  // V: 128 rows x 8 chunks
        int chunk = is * 256 + tid;
        int r = chunk >> 3, c = chunk & 7;
        gload_lds16(Vbase + (size_t)r * T_SEQ + kt0 + ((c ^ (r & 7)) << 3),
                    &Vlds[buf][(is * 256 + w * 64) * 8]);
      }
    };

    const int nkt = 2 * (qt + 1);
    int cur = 0;
    STAGE(0, 0);
    for (int kt = 0; kt < nkt; ++kt) {
      if (kt + 1 < nkt) {
        STAGE(cur ^ 1, kt + 1);
        asm volatile("s_waitcnt vmcnt(8)" ::: "memory");
      } else {
        asm volatile("s_waitcnt vmcnt(0)" ::: "memory");
      }
      __builtin_amdgcn_s_barrier();
      __builtin_amdgcn_sched_barrier(0);

      const unsigned short* Kl = Klds[cur];
      const unsigned short* Vl = Vlds[cur];
      const int kt0 = kt * 64;
      const bool alldead = (kt0 >= qbase + 32);  // wave-uniform

      if (!alldead) {
        // ---- S^T[k][q] = K_tile @ Q^T ----
        f32x16 sacc[2] = {};
#pragma unroll
        for (int ds = 0; ds < 8; ++ds) {
#pragma unroll
          for (int kf = 0; kf < 2; ++kf) {
            int row = kf * 32 + l31;
            int c = (2 * ds + hi) ^ (row & 15);
            bf16x8 kfv = *(const bf16x8*)(Kl + row * 128 + c * 8);
            sacc[kf] = __builtin_amdgcn_mfma_f32_32x32x16_bf16(kfv, qf[ds], sacc[kf], 0, 0, 0);
          }
        }

        // ---- bias + causal mask + in-register online softmax ----
        const bool masked = (kt0 + 63 > qbase);  // wave-uniform
        const float base0 = slopeL2 * (float)(kt0 + 4 * hi) - qbias;
        const int lim = qbase + l31 - kt0 - 4 * hi;
        float mx = -1e30f;
#pragma unroll
        for (int kf = 0; kf < 2; ++kf)
#pragma unroll
          for (int r = 0; r < 16; ++r) {
            const int ckoff = kf * 32 + (r & 3) + 8 * (r >> 2);
            float a = fmaf(sacc[kf][r], c0, fmaf((float)ckoff, slopeL2, base0));
            if (masked) a = (ckoff <= lim) ? a : -1e30f;
            sacc[kf][r] = a;
            mx = fmaxf(mx, a);
          }
        mx = fmaxf(mx, __shfl_xor(mx, 32, 64));
        const float mnew = fmaxf(mrun, mx);
        const float alpha = exp2f(mrun - mnew);
        mrun = mnew;
        float sm = 0.f;
#pragma unroll
        for (int kf = 0; kf < 2; ++kf)
#pragma unroll
          for (int r = 0; r < 16; ++r) {
            float p = exp2f(sacc[kf][r] - mnew);
            sacc[kf][r] = p;
            sm += p;
          }
        sm += __shfl_xor(sm, 32, 64);
        lrun = lrun * alpha + sm;
#pragma unroll
        for (int df = 0; df < 4; ++df)
#pragma unroll
          for (int r = 0; r < 16; ++r) yacc[df][r] *= alpha;

        // ---- P -> bf16 B-fragments (cvt_pk + permlane32_swap) ----
        unsigned cpk[2][8];
#pragma unroll
        for (int kf = 0; kf < 2; ++kf)
#pragma unroll
          for (int j = 0; j < 8; ++j)
            cpk[kf][j] = cvtpk(sacc[kf][2 * j], sacc[kf][2 * j + 1]);

        bf16x8 pb[4];
#pragma unroll
        for (int ks = 0; ks < 4; ++ks) {
          unsigned a0 = cpk[ks >> 1][4 * (ks & 1) + 0];
          unsigned b0 = cpk[ks >> 1][4 * (ks & 1) + 2];
          unsigned a1 = cpk[ks >> 1][4 * (ks & 1) + 1];
          unsigned b1 = cpk[ks >> 1][4 * (ks & 1) + 3];
          plswap(a0, b0);
          plswap(a1, b1);
          union { unsigned u[4]; bf16x8 v; } pk;
          pk.u[0] = a0; pk.u[1] = a1; pk.u[2] = b0; pk.u[3] = b1;
          pb[ks] = pk.v;
        }

        // ---- y^T += V^T @ P^T ----
#pragma unroll
        for (int df = 0; df < 4; ++df) {
#pragma unroll
          for (int ks = 0; ks < 4; ++ks) {
            int row = 32 * df + l31;
            int c = (2 * ks + hi) ^ (row & 7);
            bf16x8 vf = *(const bf16x8*)(Vl + row * 64 + c * 8);
            yacc[df] = __builtin_amdgcn_mfma_f32_32x32x16_bf16(vf, pb[ks], yacc[df], 0, 0, 0);
          }
        }
      }

      __builtin_amdgcn_sched_barrier(0);
      __builtin_amdgcn_s_barrier();
      cur ^= 1;
    }

    // ---- epilogue: normalize + store bf16 (y^T: lane has q=l31, d scattered) ----
    const float inv = 1.f / lrun;
#pragma unroll
    for (int df = 0; df < 4; ++df)
#pragma unroll
      for (int g = 0; g < 4; ++g) {
        unsigned u0 = cvtpk(yacc[df][4 * g + 0] * inv, yacc[df][4 * g + 1] * inv);
        unsigned u1 = cvtpk(yacc[df][4 * g + 2] * inv, yacc[df][4 * g + 3] * inv);
        union { unsigned u[2]; uint2 v; } pk;
        pk.u[0] = u0; pk.u[1] = u1;
        *(uint2*)(Y + (size_t)qrow * NE + h * HD + 32 * df + 8 * g + 4 * hi) = pk.v;
      }
  }
}

extern "C" void kernel_launch(void* const* d_in, const int* in_sizes, int n_in,
                              void* d_out, int out_size, void* d_ws, size_t ws_size,
                              hipStream_t stream) {
  const float* x = (const float*)d_in[0];
  const float* Wq = (const float*)d_in[1];
  const float* Wk = (const float*)d_in[2];
  const float* Wv = (const float*)d_in[3];
  const float* Wo = (const float*)d_in[4];

  unsigned short* ws = (unsigned short*)d_ws;
  unsigned short* xb  = ws;               // x bf16 [8192][2048]; reused as Y
  unsigned short* Wqt = ws + 16777216;
  unsigned short* Wkt = ws + 20971520;
  unsigned short* Wvt = ws + 22020096;
  unsigned short* Wot = ws + 23068672;
  unsigned short* Qb  = ws + 27262976;
  unsigned short* Kb  = ws + 44040192;
  unsigned short* Vtb = ws + 48234496;
  unsigned short* Yb  = xb;

  k_cast<<<8192, 256, 0, stream>>>(x, xb, 16777216);
  k_transpose_cast<<<dim3(64, 64), 256, 0, stream>>>(Wq, Wqt, 2048, 2048);
  k_transpose_cast<<<dim3(16, 64), 256, 0, stream>>>(Wk, Wkt, 2048, 512);
  k_transpose_cast<<<dim3(16, 64), 256, 0, stream>>>(Wv, Wvt, 2048, 512);
  k_transpose_cast<<<dim3(64, 64), 256, 0, stream>>>(Wo, Wot, 2048, 2048);

  k_gemm<0><<<dim3(16, 64), 256, 0, stream>>>(xb, Wqt, Qb, MTOT, 2048, 2048);
  k_gemm<0><<<dim3(4, 64), 256, 0, stream>>>(xb, Wkt, Kb, MTOT, 512, 2048);
  k_gemm<1><<<dim3(4, 64), 256, 0, stream>>>(xb, Wvt, Vtb, MTOT, 512, 2048);

  k_attn<<<dim3(8, 16, 4), 256, 0, stream>>>(Qb, Kb, Vtb, Yb);

  k_gemm<2><<<dim3(16, 64), 256, 0, stream>>>(Yb, Wot, d_out, MTOT, 2048, 2048);
}